// Round 2
// baseline (655.464 us; speedup 1.0000x reference)
//
#include <hip/hip_runtime.h>
#include <hip/hip_bf16.h>
#include <stdint.h>

// bf16-MFMA pipeline, round 2.
// Flash rewrite: S^T trick (mfma(K,Q)) so P's C-layout quads are A-frag
// k-runs; non-online softmax (scores bounded ~|s|<3, exp overflow-safe);
// per-lane l accumulation; wave-private lP (no barrier). cvt_wt now a tiled
// transpose (old one was stride-12KB uncoalesced).
//
// ws layout (92.3 MB):
//   xb      [8192][1024] bf16   @ 0
//   wqkv_t  [3072][1024] bf16   @ 16777216
//   wout_t  [1024][1024] bf16   @ 23068672
//   Qs      [16][4096][128] bf16 (pre-scaled 1/32) @ 25165824
//   Ks      [16][4096][128] bf16 @ 41943040
//   Vt      [16][128][4096] bf16 @ 58720256
//   Ob      [8192][1024] bf16   @ 75497472

typedef __attribute__((ext_vector_type(8))) short short8;
typedef __attribute__((ext_vector_type(4))) float f32x4;

#define SCALE_Q 0.03125f

__device__ __forceinline__ unsigned short f2bf(float f) {
  union { float f; unsigned int u; } v;
  v.f = f;
  return (unsigned short)((v.u + 0x7fffu + ((v.u >> 16) & 1u)) >> 16);
}

__device__ __forceinline__ unsigned int pkbf2(float a, float b) {
  __hip_bfloat162 h = __float22bfloat162_rn(make_float2(a, b));
  union { __hip_bfloat162 h; unsigned int u; } c;
  c.h = h;
  return c.u;  // a in low 16, b in high 16
}

__device__ __forceinline__ void gload_lds16(const void* g, void* l) {
  __builtin_amdgcn_global_load_lds(
      (const __attribute__((address_space(1))) uint32_t*)(uintptr_t)g,
      (__attribute__((address_space(3))) uint32_t*)(uintptr_t)l, 16, 0, 0);
}

__device__ __forceinline__ f32x4 zero4() {
  f32x4 z; z.x = 0.f; z.y = 0.f; z.z = 0.f; z.w = 0.f; return z;
}

// ---------------- conversions ----------------
__global__ __launch_bounds__(256) void k_cvt_x(const float* __restrict__ in,
                                               unsigned short* __restrict__ out) {
  const int t = blockIdx.x * 256 + threadIdx.x;
  const float4 v = ((const float4*)in)[t];
  ushort4 o;
  o.x = f2bf(v.x); o.y = f2bf(v.y); o.z = f2bf(v.z); o.w = f2bf(v.w);
  ((ushort4*)out)[t] = o;
}

// wt[n][k] = bf16(w[k][n]); K fixed 1024. Tiled 32x32 transpose, coalesced
// both directions (old version read stride-4*Nn => ~16x overfetch).
__global__ __launch_bounds__(256) void k_cvt_wt(const float* __restrict__ w,
                                                unsigned short* __restrict__ wt,
                                                int Nn) {
  __shared__ float t[32][33];
  const int n0 = blockIdx.x << 5, k0 = blockIdx.y << 5;
  const int c = threadIdx.x & 31, r8 = threadIdx.x >> 5;
#pragma unroll
  for (int i = 0; i < 4; ++i) {
    const int r = (i << 3) + r8;
    t[r][c] = w[(long)(k0 + r) * Nn + n0 + c];
  }
  __syncthreads();
#pragma unroll
  for (int i = 0; i < 4; ++i) {
    const int r = (i << 3) + r8;
    wt[(long)(n0 + r) * 1024 + k0 + c] = f2bf(t[c][r]);
  }
}

// ---------------- QKV GEMM: C[8192][3072] = xb @ wqkv_t^T ----------------
__global__ __launch_bounds__(256, 2) void k_qkv_gemm(
    const unsigned short* __restrict__ A,   // [8192][1024]
    const unsigned short* __restrict__ Bt,  // [3072][1024]
    unsigned short* __restrict__ Qs, unsigned short* __restrict__ Ks,
    unsigned short* __restrict__ Vt) {
  __shared__ __align__(16) unsigned short lA[4][128][8];
  __shared__ __align__(16) unsigned short lB[4][128][8];
  const int tid = threadIdx.x;
  const int w = tid >> 6, ln = tid & 63;
  const int m15 = ln & 15, q4 = ln >> 4;
  const int wm = (w >> 1) << 6, wn = (w & 1) << 6;
  const int tn = blockIdx.x, tm = blockIdx.y;

  f32x4 acc[4][4];
#pragma unroll
  for (int i = 0; i < 4; ++i)
#pragma unroll
    for (int j = 0; j < 4; ++j) acc[i][j] = zero4();

  for (int kb = 0; kb < 1024; kb += 32) {
    __syncthreads();
#pragma unroll
    for (int c = 0; c < 2; ++c) {
      const int p = ((c * 4 + w) << 10) + (ln << 4);
      const int g = p >> 11;
      const int r = (p & 2047) >> 4;
      gload_lds16(A + ((long)tm * 128 + r) * 1024 + kb + g * 8,
                  (char*)&lA[0][0][0] + p);
      gload_lds16(Bt + ((long)tn * 128 + r) * 1024 + kb + g * 8,
                  (char*)&lB[0][0][0] + p);
    }
    __syncthreads();
    short8 afr[4], bfr[4];
#pragma unroll
    for (int i = 0; i < 4; ++i)
      afr[i] = *(const short8*)&lA[q4][wm + i * 16 + m15][0];
#pragma unroll
    for (int j = 0; j < 4; ++j)
      bfr[j] = *(const short8*)&lB[q4][wn + j * 16 + m15][0];
#pragma unroll
    for (int i = 0; i < 4; ++i)
#pragma unroll
      for (int j = 0; j < 4; ++j)
        acc[i][j] = __builtin_amdgcn_mfma_f32_16x16x32_bf16(afr[i], bfr[j],
                                                            acc[i][j], 0, 0, 0);
  }

  const int which = tn >> 3;
  const int h = tn & 7;
#pragma unroll
  for (int i = 0; i < 4; ++i) {
#pragma unroll
    for (int r = 0; r < 4; ++r) {
      const int m = (tm << 7) + wm + (i << 4) + (q4 << 2) + r;
      const int b = m >> 12, row = m & 4095;
      const long bh = b * 8 + h;
#pragma unroll
      for (int j = 0; j < 4; ++j) {
        const int dd = wn + (j << 4) + m15;
        const float val = acc[i][j][r];
        if (which == 0)
          Qs[(bh * 4096 + row) * 128 + dd] = f2bf(val * SCALE_Q);
        else if (which == 1)
          Ks[(bh * 4096 + row) * 128 + dd] = f2bf(val);
        else
          Vt[(bh * 128 + dd) * 4096 + row] = f2bf(val);
      }
    }
  }
}

// ---------------- flash attention (S^T form) ----------------
// grid (64 rowblocks, 16 bh); block 256 = 4 waves; wave owns 16 Q rows.
// S^T = mfma(K-frag, Q-frag): lane holds S^T[j=q4*4+r][qrow=m15] -> the 4
// r-values are consecutive j = A-frag k-run for PV. Non-online softmax.
__global__ __launch_bounds__(256, 3) void k_flash(
    const unsigned short* __restrict__ Qs, const unsigned short* __restrict__ Ks,
    const unsigned short* __restrict__ Vt, const int* __restrict__ mask,
    unsigned short* __restrict__ Ob) {
  __shared__ __align__(16) unsigned short lK[16][64][8];   // 16 KB
  __shared__ __align__(16) unsigned short lV[8][128][8];   // 16 KB
  __shared__ __align__(16) unsigned short lP[4][16][72];   // 9 KB, per-wave

  const int tid = threadIdx.x;
  const int w = tid >> 6, ln = tid & 63;
  const int m15 = ln & 15, q4 = ln >> 4;
  const int bh = blockIdx.y;
  const int rowblk = blockIdx.x;

  const unsigned short* Qbh = Qs + (long)bh * 524288;
  const unsigned short* Kbh = Ks + (long)bh * 524288;
  const unsigned short* Vbh = Vt + (long)bh * 524288;

  const int qrow = rowblk * 64 + w * 16 + m15;  // this lane's q-row (for S^T)

  short8 qf[4];
#pragma unroll
  for (int kk = 0; kk < 4; ++kk)
    qf[kk] = *(const short8*)(Qbh + (long)qrow * 128 + kk * 32 + q4 * 8);

  f32x4 o[8];
#pragma unroll
  for (int j = 0; j < 8; ++j) o[j] = zero4();
  f32x4 lacc = zero4();

  const bool maskrows = rowblk < 32;  // all 64 rows < 2048, uniform per block

  for (int kv = 0; kv < 4096; kv += 64) {
    __syncthreads();
#pragma unroll
    for (int c = 0; c < 4; ++c) {
      const int p = ((c * 4 + w) << 10) + (ln << 4);
      const int cs = p >> 10;
      const int j = (p & 1023) >> 4;
      gload_lds16(Kbh + (long)(kv + j) * 128 + cs * 8, (char*)&lK[0][0][0] + p);
      const int cv = p >> 11;
      const int dv = (p & 2047) >> 4;
      gload_lds16(Vbh + (long)dv * 4096 + kv + cv * 8, (char*)&lV[0][0][0] + p);
    }
    __syncthreads();

    // S^T = K Q^T : s[jt][r] = S[qrow=m15][j = kv + jt*16 + q4*4 + r]
    f32x4 s[4];
#pragma unroll
    for (int jt = 0; jt < 4; ++jt) s[jt] = zero4();
#pragma unroll
    for (int jt = 0; jt < 4; ++jt) {
#pragma unroll
      for (int kk = 0; kk < 4; ++kk) {
        const short8 kfr = *(const short8*)&lK[kk * 4 + q4][jt * 16 + m15][0];
        s[jt] = __builtin_amdgcn_mfma_f32_16x16x32_bf16(kfr, qf[kk], s[jt],
                                                        0, 0, 0);
      }
    }

    if (maskrows && kv < 2048) {
#pragma unroll
      for (int jt = 0; jt < 4; ++jt) {
        const int4 mv = *(const int4*)&mask[(long)qrow * 2048 + kv + jt * 16 + q4 * 4];
        s[jt].x = mv.x ? s[jt].x : -1e30f;
        s[jt].y = mv.y ? s[jt].y : -1e30f;
        s[jt].z = mv.z ? s[jt].z : -1e30f;
        s[jt].w = mv.w ? s[jt].w : -1e30f;
      }
    }

    // p = exp(s) directly (|s| < ~3 for unmasked; masked -> 0). Per-lane l.
    unsigned int pk[4][2];
#pragma unroll
    for (int jt = 0; jt < 4; ++jt) {
      f32x4 p;
      p.x = __expf(s[jt].x); p.y = __expf(s[jt].y);
      p.z = __expf(s[jt].z); p.w = __expf(s[jt].w);
      lacc.x += p.x; lacc.y += p.y; lacc.z += p.z; lacc.w += p.w;
      pk[jt][0] = pkbf2(p.x, p.y);
      pk[jt][1] = pkbf2(p.z, p.w);
    }

    // P -> wave-private LDS (b64 per jt), read back as A-frags (b128).
#pragma unroll
    for (int jt = 0; jt < 4; ++jt) {
      uint2 u; u.x = pk[jt][0]; u.y = pk[jt][1];
      *(uint2*)&lP[w][m15][jt * 16 + q4 * 4] = u;
    }
    __asm__ volatile("s_waitcnt lgkmcnt(0)" ::: "memory");

#pragma unroll
    for (int kk2 = 0; kk2 < 2; ++kk2) {
      const short8 pf = *(const short8*)&lP[w][m15][kk2 * 32 + q4 * 8];
#pragma unroll
      for (int jt2 = 0; jt2 < 8; ++jt2) {
        const short8 vf = *(const short8*)&lV[kk2 * 4 + q4][jt2 * 16 + m15][0];
        o[jt2] = __builtin_amdgcn_mfma_f32_16x16x32_bf16(pf, vf, o[jt2],
                                                         0, 0, 0);
      }
    }
  }

  // l: per-lane horizontal + reduce over q4 group (lanes m15 share qrow)
  float lh = lacc.x + lacc.y + lacc.z + lacc.w;
  lh += __shfl_xor(lh, 16);
  lh += __shfl_xor(lh, 32);
  const float linv = 1.0f / lh;

  // o is C-layout: lane holds O[qrow' = base + q4*4 + r][d = jt2*16 + m15].
  float linv_r[4];
#pragma unroll
  for (int r = 0; r < 4; ++r) linv_r[r] = __shfl(linv, q4 * 4 + r);

  const int b = bh >> 3, h = bh & 7;
#pragma unroll
  for (int r = 0; r < 4; ++r) {
    const int row = rowblk * 64 + w * 16 + q4 * 4 + r;
    unsigned short* op = Ob + ((long)(b * 4096 + row)) * 1024 + h * 128;
#pragma unroll
    for (int jt2 = 0; jt2 < 8; ++jt2)
      op[jt2 * 16 + m15] = f2bf(o[jt2][r] * linv_r[r]);
  }
}

// ---------------- out projection ----------------
__global__ __launch_bounds__(256, 2) void k_proj_gemm(
    const unsigned short* __restrict__ A,   // [8192][1024]
    const unsigned short* __restrict__ Bt,  // [1024][1024]
    const float* __restrict__ bias, float* __restrict__ Out) {
  __shared__ __align__(16) unsigned short lA[4][128][8];
  __shared__ __align__(16) unsigned short lB[4][128][8];
  const int tid = threadIdx.x;
  const int w = tid >> 6, ln = tid & 63;
  const int m15 = ln & 15, q4 = ln >> 4;
  const int wm = (w >> 1) << 6, wn = (w & 1) << 6;
  const int tn = blockIdx.x, tm = blockIdx.y;

  f32x4 acc[4][4];
#pragma unroll
  for (int i = 0; i < 4; ++i)
#pragma unroll
    for (int j = 0; j < 4; ++j) acc[i][j] = zero4();

  for (int kb = 0; kb < 1024; kb += 32) {
    __syncthreads();
#pragma unroll
    for (int c = 0; c < 2; ++c) {
      const int p = ((c * 4 + w) << 10) + (ln << 4);
      const int g = p >> 11;
      const int r = (p & 2047) >> 4;
      gload_lds16(A + ((long)tm * 128 + r) * 1024 + kb + g * 8,
                  (char*)&lA[0][0][0] + p);
      gload_lds16(Bt + ((long)tn * 128 + r) * 1024 + kb + g * 8,
                  (char*)&lB[0][0][0] + p);
    }
    __syncthreads();
    short8 afr[4], bfr[4];
#pragma unroll
    for (int i = 0; i < 4; ++i)
      afr[i] = *(const short8*)&lA[q4][wm + i * 16 + m15][0];
#pragma unroll
    for (int j = 0; j < 4; ++j)
      bfr[j] = *(const short8*)&lB[q4][wn + j * 16 + m15][0];
#pragma unroll
    for (int i = 0; i < 4; ++i)
#pragma unroll
      for (int j = 0; j < 4; ++j)
        acc[i][j] = __builtin_amdgcn_mfma_f32_16x16x32_bf16(afr[i], bfr[j],
                                                            acc[i][j], 0, 0, 0);
  }

#pragma unroll
  for (int i = 0; i < 4; ++i)
#pragma unroll
    for (int r = 0; r < 4; ++r) {
      const int m = (tm << 7) + wm + (i << 4) + (q4 << 2) + r;
#pragma unroll
      for (int j = 0; j < 4; ++j) {
        const int n = (tn << 7) + wn + (j << 4) + m15;
        Out[(long)m * 1024 + n] = acc[i][j][r] + bias[n];
      }
    }
}

extern "C" void kernel_launch(void* const* d_in, const int* in_sizes, int n_in,
                              void* d_out, int out_size, void* d_ws,
                              size_t ws_size, hipStream_t stream) {
  const float* x = (const float*)d_in[0];
  const float* Wqkv = (const float*)d_in[1];
  const float* Wout = (const float*)d_in[2];
  const float* bout = (const float*)d_in[3];
  const int* mask = (const int*)d_in[4];
  float* out = (float*)d_out;

  char* ws = (char*)d_ws;
  unsigned short* xb     = (unsigned short*)(ws);
  unsigned short* wqkv_t = (unsigned short*)(ws + 16777216);
  unsigned short* wout_t = (unsigned short*)(ws + 23068672);
  unsigned short* Qs     = (unsigned short*)(ws + 25165824);
  unsigned short* Ks     = (unsigned short*)(ws + 41943040);
  unsigned short* Vt     = (unsigned short*)(ws + 58720256);
  unsigned short* Ob     = (unsigned short*)(ws + 75497472);

  hipLaunchKernelGGL(k_cvt_x, dim3(8192), dim3(256), 0, stream, x, xb);
  hipLaunchKernelGGL(k_cvt_wt, dim3(96, 32), dim3(256), 0, stream, Wqkv, wqkv_t, 3072);
  hipLaunchKernelGGL(k_cvt_wt, dim3(32, 32), dim3(256), 0, stream, Wout, wout_t, 1024);
  hipLaunchKernelGGL(k_qkv_gemm, dim3(24, 64), dim3(256), 0, stream,
                     xb, wqkv_t, Qs, Ks, Vt);
  hipLaunchKernelGGL(k_flash, dim3(64, 16), dim3(256), 0, stream,
                     Qs, Ks, Vt, mask, Ob);
  hipLaunchKernelGGL(k_proj_gemm, dim3(8, 64), dim3(256), 0, stream,
                     Ob, wout_t, bout, out);
}

// Round 3
// 486.968 us; speedup vs baseline: 1.3460x; 1.3460x over previous
//
#include <hip/hip_runtime.h>
#include <hip/hip_bf16.h>
#include <stdint.h>

// Round 3: flash back to 128 Q-rows/block (restores KV staging amortization
// that round 2 halved), keeping S^T trick + non-online softmax. qkv_gemm now
// stores V coalesced; separate tiled k_vtrans builds Vt (round 2's in-gemm
// V^T scatter wrote 2B stores at 8KB stride).
//
// ws layout (92.3 MB):
//   xb/Ob   [8192][1024] bf16   @ 0          (Ob overlays xb; xb dead by flash)
//   wqkv_t  [3072][1024] bf16   @ 16777216
//   wout_t  [1024][1024] bf16   @ 23068672
//   Qs      [16][4096][128] bf16 (pre-scaled 1/32) @ 25165824
//   Ks      [16][4096][128] bf16 @ 41943040
//   Vt      [16][128][4096] bf16 @ 58720256
//   Vs      [16][4096][128] bf16 @ 75497472

typedef __attribute__((ext_vector_type(8))) short short8;
typedef __attribute__((ext_vector_type(4))) float f32x4;

#define SCALE_Q 0.03125f

__device__ __forceinline__ unsigned short f2bf(float f) {
  union { float f; unsigned int u; } v;
  v.f = f;
  return (unsigned short)((v.u + 0x7fffu + ((v.u >> 16) & 1u)) >> 16);
}

__device__ __forceinline__ unsigned int pkbf2(float a, float b) {
  __hip_bfloat162 h = __float22bfloat162_rn(make_float2(a, b));
  union { __hip_bfloat162 h; unsigned int u; } c;
  c.h = h;
  return c.u;
}

__device__ __forceinline__ void gload_lds16(const void* g, void* l) {
  __builtin_amdgcn_global_load_lds(
      (const __attribute__((address_space(1))) uint32_t*)(uintptr_t)g,
      (__attribute__((address_space(3))) uint32_t*)(uintptr_t)l, 16, 0, 0);
}

__device__ __forceinline__ f32x4 zero4() {
  f32x4 z; z.x = 0.f; z.y = 0.f; z.z = 0.f; z.w = 0.f; return z;
}

// ---------------- conversions ----------------
__global__ __launch_bounds__(256) void k_cvt_x(const float* __restrict__ in,
                                               unsigned short* __restrict__ out) {
  const int t = blockIdx.x * 256 + threadIdx.x;
  const float4 v = ((const float4*)in)[t];
  ushort4 o;
  o.x = f2bf(v.x); o.y = f2bf(v.y); o.z = f2bf(v.z); o.w = f2bf(v.w);
  ((ushort4*)out)[t] = o;
}

__global__ __launch_bounds__(256) void k_cvt_wt(const float* __restrict__ w,
                                                unsigned short* __restrict__ wt,
                                                int Nn) {
  __shared__ float t[32][33];
  const int n0 = blockIdx.x << 5, k0 = blockIdx.y << 5;
  const int c = threadIdx.x & 31, r8 = threadIdx.x >> 5;
#pragma unroll
  for (int i = 0; i < 4; ++i) {
    const int r = (i << 3) + r8;
    t[r][c] = w[(long)(k0 + r) * Nn + n0 + c];
  }
  __syncthreads();
#pragma unroll
  for (int i = 0; i < 4; ++i) {
    const int r = (i << 3) + r8;
    wt[(long)(n0 + r) * 1024 + k0 + c] = f2bf(t[c][r]);
  }
}

// ---------------- QKV GEMM ----------------
__global__ __launch_bounds__(256, 2) void k_qkv_gemm(
    const unsigned short* __restrict__ A,   // [8192][1024]
    const unsigned short* __restrict__ Bt,  // [3072][1024]
    unsigned short* __restrict__ Qs, unsigned short* __restrict__ Ks,
    unsigned short* __restrict__ Vs) {
  __shared__ __align__(16) unsigned short lA[4][128][8];
  __shared__ __align__(16) unsigned short lB[4][128][8];
  const int tid = threadIdx.x;
  const int w = tid >> 6, ln = tid & 63;
  const int m15 = ln & 15, q4 = ln >> 4;
  const int wm = (w >> 1) << 6, wn = (w & 1) << 6;
  const int tn = blockIdx.x, tm = blockIdx.y;

  f32x4 acc[4][4];
#pragma unroll
  for (int i = 0; i < 4; ++i)
#pragma unroll
    for (int j = 0; j < 4; ++j) acc[i][j] = zero4();

  for (int kb = 0; kb < 1024; kb += 32) {
    __syncthreads();
#pragma unroll
    for (int c = 0; c < 2; ++c) {
      const int p = ((c * 4 + w) << 10) + (ln << 4);
      const int g = p >> 11;
      const int r = (p & 2047) >> 4;
      gload_lds16(A + ((long)tm * 128 + r) * 1024 + kb + g * 8,
                  (char*)&lA[0][0][0] + p);
      gload_lds16(Bt + ((long)tn * 128 + r) * 1024 + kb + g * 8,
                  (char*)&lB[0][0][0] + p);
    }
    __syncthreads();
    short8 afr[4], bfr[4];
#pragma unroll
    for (int i = 0; i < 4; ++i)
      afr[i] = *(const short8*)&lA[q4][wm + i * 16 + m15][0];
#pragma unroll
    for (int j = 0; j < 4; ++j)
      bfr[j] = *(const short8*)&lB[q4][wn + j * 16 + m15][0];
#pragma unroll
    for (int i = 0; i < 4; ++i)
#pragma unroll
      for (int j = 0; j < 4; ++j)
        acc[i][j] = __builtin_amdgcn_mfma_f32_16x16x32_bf16(afr[i], bfr[j],
                                                            acc[i][j], 0, 0, 0);
  }

  const int which = tn >> 3;
  const int h = tn & 7;
#pragma unroll
  for (int i = 0; i < 4; ++i) {
#pragma unroll
    for (int r = 0; r < 4; ++r) {
      const int m = (tm << 7) + wm + (i << 4) + (q4 << 2) + r;
      const int b = m >> 12, row = m & 4095;
      const long bh = b * 8 + h;
#pragma unroll
      for (int j = 0; j < 4; ++j) {
        const int dd = wn + (j << 4) + m15;
        const float val = acc[i][j][r];
        if (which == 0)
          Qs[(bh * 4096 + row) * 128 + dd] = f2bf(val * SCALE_Q);
        else if (which == 1)
          Ks[(bh * 4096 + row) * 128 + dd] = f2bf(val);
        else
          Vs[(bh * 4096 + row) * 128 + dd] = f2bf(val);  // coalesced now
      }
    }
  }
}

// ---------------- V transpose: Vs[bh][n][d] -> Vt[bh][d][n] ----------------
__global__ __launch_bounds__(256) void k_vtrans(
    const unsigned short* __restrict__ Vs, unsigned short* __restrict__ Vt) {
  __shared__ unsigned short t[64][66];
  const int n0 = blockIdx.x << 6, d0 = blockIdx.y << 6, bh = blockIdx.z;
  const int tt = threadIdx.x;
  const int nr = tt >> 2, dc = (tt & 3) << 4;
  const unsigned short* src = Vs + (((long)bh * 4096 + n0 + nr) << 7) + d0 + dc;
  *(short8*)&t[nr][dc] = *(const short8*)src;
  *(short8*)&t[nr][dc + 8] = *(const short8*)(src + 8);
  __syncthreads();
  const int dr = tt >> 2, nc = (tt & 3) << 4;
  short8 a, b;
#pragma unroll
  for (int jj = 0; jj < 8; ++jj) a[jj] = (short)t[nc + jj][dr];
#pragma unroll
  for (int jj = 0; jj < 8; ++jj) b[jj] = (short)t[nc + 8 + jj][dr];
  unsigned short* dst = Vt + (((long)bh * 128 + d0 + dr) << 12) + n0 + nc;
  *(short8*)dst = a;
  *(short8*)(dst + 8) = b;
}

// ---------------- flash attention (S^T, 128 rows/block) ----------------
// grid (32 rowblocks, 16 bh); block 256 = 4 waves; wave owns 32 Q rows as two
// 16-row groups. S^T = mfma(K-frag, Q-frag): lane m15 = q-within-group, quad
// r = 4 consecutive j -> A-frag k-run for PV via wave-private lP.
__global__ __launch_bounds__(256, 2) void k_flash(
    const unsigned short* __restrict__ Qs, const unsigned short* __restrict__ Ks,
    const unsigned short* __restrict__ Vt, const int* __restrict__ mask,
    unsigned short* __restrict__ Ob) {
  __shared__ __align__(16) unsigned short lK[16][64][8];   // 16 KB
  __shared__ __align__(16) unsigned short lV[8][128][8];   // 16 KB
  __shared__ __align__(16) unsigned short lP[4][32][72];   // 18 KB

  const int tid = threadIdx.x;
  const int w = tid >> 6, ln = tid & 63;
  const int m15 = ln & 15, q4 = ln >> 4;
  const int bh = blockIdx.y;
  const int rowblk = blockIdx.x;
  const int rbase = rowblk * 128 + w * 32;  // wave's 32-row base

  const unsigned short* Qbh = Qs + (long)bh * 524288;
  const unsigned short* Kbh = Ks + (long)bh * 524288;
  const unsigned short* Vbh = Vt + (long)bh * 524288;

  short8 qf[2][4];
#pragma unroll
  for (int i = 0; i < 2; ++i)
#pragma unroll
    for (int kk = 0; kk < 4; ++kk)
      qf[i][kk] = *(const short8*)(Qbh +
          (long)(rbase + i * 16 + m15) * 128 + kk * 32 + q4 * 8);

  f32x4 o[2][8];
#pragma unroll
  for (int i = 0; i < 2; ++i)
#pragma unroll
    for (int j = 0; j < 8; ++j) o[i][j] = zero4();
  f32x4 lacc[2];
  lacc[0] = zero4(); lacc[1] = zero4();

  const bool maskrows = rowblk < 16;

  for (int kv = 0; kv < 4096; kv += 64) {
    __syncthreads();
#pragma unroll
    for (int c = 0; c < 4; ++c) {
      const int p = ((c * 4 + w) << 10) + (ln << 4);
      const int cs = p >> 10;
      const int j = (p & 1023) >> 4;
      gload_lds16(Kbh + (long)(kv + j) * 128 + cs * 8, (char*)&lK[0][0][0] + p);
      const int cv = p >> 11;
      const int dv = (p & 2047) >> 4;
      gload_lds16(Vbh + (long)dv * 4096 + kv + cv * 8, (char*)&lV[0][0][0] + p);
    }
    __syncthreads();

    // S^T = K Q^T : s[i][jt][r] = S[q = rbase+i*16+m15][j = kv+jt*16+q4*4+r]
    f32x4 s[2][4];
#pragma unroll
    for (int i = 0; i < 2; ++i)
#pragma unroll
      for (int jt = 0; jt < 4; ++jt) s[i][jt] = zero4();
#pragma unroll
    for (int jt = 0; jt < 4; ++jt) {
      short8 kfr[4];
#pragma unroll
      for (int kk = 0; kk < 4; ++kk)
        kfr[kk] = *(const short8*)&lK[kk * 4 + q4][jt * 16 + m15][0];
#pragma unroll
      for (int i = 0; i < 2; ++i)
#pragma unroll
        for (int kk = 0; kk < 4; ++kk)
          s[i][jt] = __builtin_amdgcn_mfma_f32_16x16x32_bf16(kfr[kk], qf[i][kk],
                                                             s[i][jt], 0, 0, 0);
    }

    if (maskrows && kv < 2048) {
#pragma unroll
      for (int i = 0; i < 2; ++i) {
        const int qrow = rbase + i * 16 + m15;
#pragma unroll
        for (int jt = 0; jt < 4; ++jt) {
          const int4 mv =
              *(const int4*)&mask[(long)qrow * 2048 + kv + jt * 16 + q4 * 4];
          s[i][jt].x = mv.x ? s[i][jt].x : -1e30f;
          s[i][jt].y = mv.y ? s[i][jt].y : -1e30f;
          s[i][jt].z = mv.z ? s[i][jt].z : -1e30f;
          s[i][jt].w = mv.w ? s[i][jt].w : -1e30f;
        }
      }
    }

    // p = exp(s); per-lane l accumulation; pack + wave-private LDS writes.
#pragma unroll
    for (int i = 0; i < 2; ++i) {
#pragma unroll
      for (int jt = 0; jt < 4; ++jt) {
        f32x4 p;
        p.x = __expf(s[i][jt].x); p.y = __expf(s[i][jt].y);
        p.z = __expf(s[i][jt].z); p.w = __expf(s[i][jt].w);
        lacc[i].x += p.x; lacc[i].y += p.y;
        lacc[i].z += p.z; lacc[i].w += p.w;
        uint2 u;
        u.x = pkbf2(p.x, p.y);
        u.y = pkbf2(p.z, p.w);
        *(uint2*)&lP[w][i * 16 + m15][jt * 16 + q4 * 4] = u;
      }
    }
    __asm__ volatile("s_waitcnt lgkmcnt(0)" ::: "memory");

    // O += P @ V
#pragma unroll
    for (int kk2 = 0; kk2 < 2; ++kk2) {
      short8 pf[2];
#pragma unroll
      for (int i = 0; i < 2; ++i)
        pf[i] = *(const short8*)&lP[w][i * 16 + m15][kk2 * 32 + q4 * 8];
#pragma unroll
      for (int jt2 = 0; jt2 < 8; ++jt2) {
        const short8 vf = *(const short8*)&lV[kk2 * 4 + q4][jt2 * 16 + m15][0];
#pragma unroll
        for (int i = 0; i < 2; ++i)
          o[i][jt2] = __builtin_amdgcn_mfma_f32_16x16x32_bf16(pf[i], vf,
                                                              o[i][jt2], 0, 0, 0);
      }
    }
  }

  const int b = bh >> 3, h = bh & 7;
#pragma unroll
  for (int i = 0; i < 2; ++i) {
    float lh = lacc[i].x + lacc[i].y + lacc[i].z + lacc[i].w;
    lh += __shfl_xor(lh, 16);
    lh += __shfl_xor(lh, 32);
    const float linv = 1.0f / lh;
    float linv_r[4];
#pragma unroll
    for (int r = 0; r < 4; ++r) linv_r[r] = __shfl(linv, q4 * 4 + r);
#pragma unroll
    for (int r = 0; r < 4; ++r) {
      const int row = rbase + i * 16 + q4 * 4 + r;
      unsigned short* op = Ob + ((long)(b * 4096 + row)) * 1024 + h * 128;
#pragma unroll
      for (int jt2 = 0; jt2 < 8; ++jt2)
        op[jt2 * 16 + m15] = f2bf(o[i][jt2][r] * linv_r[r]);
    }
  }
}

// ---------------- out projection ----------------
__global__ __launch_bounds__(256, 2) void k_proj_gemm(
    const unsigned short* __restrict__ A,   // [8192][1024]
    const unsigned short* __restrict__ Bt,  // [1024][1024]
    const float* __restrict__ bias, float* __restrict__ Out) {
  __shared__ __align__(16) unsigned short lA[4][128][8];
  __shared__ __align__(16) unsigned short lB[4][128][8];
  const int tid = threadIdx.x;
  const int w = tid >> 6, ln = tid & 63;
  const int m15 = ln & 15, q4 = ln >> 4;
  const int wm = (w >> 1) << 6, wn = (w & 1) << 6;
  const int tn = blockIdx.x, tm = blockIdx.y;

  f32x4 acc[4][4];
#pragma unroll
  for (int i = 0; i < 4; ++i)
#pragma unroll
    for (int j = 0; j < 4; ++j) acc[i][j] = zero4();

  for (int kb = 0; kb < 1024; kb += 32) {
    __syncthreads();
#pragma unroll
    for (int c = 0; c < 2; ++c) {
      const int p = ((c * 4 + w) << 10) + (ln << 4);
      const int g = p >> 11;
      const int r = (p & 2047) >> 4;
      gload_lds16(A + ((long)tm * 128 + r) * 1024 + kb + g * 8,
                  (char*)&lA[0][0][0] + p);
      gload_lds16(Bt + ((long)tn * 128 + r) * 1024 + kb + g * 8,
                  (char*)&lB[0][0][0] + p);
    }
    __syncthreads();
    short8 afr[4], bfr[4];
#pragma unroll
    for (int i = 0; i < 4; ++i)
      afr[i] = *(const short8*)&lA[q4][wm + i * 16 + m15][0];
#pragma unroll
    for (int j = 0; j < 4; ++j)
      bfr[j] = *(const short8*)&lB[q4][wn + j * 16 + m15][0];
#pragma unroll
    for (int i = 0; i < 4; ++i)
#pragma unroll
      for (int j = 0; j < 4; ++j)
        acc[i][j] = __builtin_amdgcn_mfma_f32_16x16x32_bf16(afr[i], bfr[j],
                                                            acc[i][j], 0, 0, 0);
  }

#pragma unroll
  for (int i = 0; i < 4; ++i)
#pragma unroll
    for (int r = 0; r < 4; ++r) {
      const int m = (tm << 7) + wm + (i << 4) + (q4 << 2) + r;
#pragma unroll
      for (int j = 0; j < 4; ++j) {
        const int n = (tn << 7) + wn + (j << 4) + m15;
        Out[(long)m * 1024 + n] = acc[i][j][r] + bias[n];
      }
    }
}

extern "C" void kernel_launch(void* const* d_in, const int* in_sizes, int n_in,
                              void* d_out, int out_size, void* d_ws,
                              size_t ws_size, hipStream_t stream) {
  const float* x = (const float*)d_in[0];
  const float* Wqkv = (const float*)d_in[1];
  const float* Wout = (const float*)d_in[2];
  const float* bout = (const float*)d_in[3];
  const int* mask = (const int*)d_in[4];
  float* out = (float*)d_out;

  char* ws = (char*)d_ws;
  unsigned short* xb     = (unsigned short*)(ws);            // also Ob
  unsigned short* wqkv_t = (unsigned short*)(ws + 16777216);
  unsigned short* wout_t = (unsigned short*)(ws + 23068672);
  unsigned short* Qs     = (unsigned short*)(ws + 25165824);
  unsigned short* Ks     = (unsigned short*)(ws + 41943040);
  unsigned short* Vt     = (unsigned short*)(ws + 58720256);
  unsigned short* Vs     = (unsigned short*)(ws + 75497472);
  unsigned short* Ob     = xb;  // xb dead after qkv_gemm

  hipLaunchKernelGGL(k_cvt_x, dim3(8192), dim3(256), 0, stream, x, xb);
  hipLaunchKernelGGL(k_cvt_wt, dim3(96, 32), dim3(256), 0, stream, Wqkv, wqkv_t, 3072);
  hipLaunchKernelGGL(k_cvt_wt, dim3(32, 32), dim3(256), 0, stream, Wout, wout_t, 1024);
  hipLaunchKernelGGL(k_qkv_gemm, dim3(24, 64), dim3(256), 0, stream,
                     xb, wqkv_t, Qs, Ks, Vs);
  hipLaunchKernelGGL(k_vtrans, dim3(64, 2, 16), dim3(256), 0, stream, Vs, Vt);
  hipLaunchKernelGGL(k_flash, dim3(32, 16), dim3(256), 0, stream,
                     Qs, Ks, Vt, mask, Ob);
  hipLaunchKernelGGL(k_proj_gemm, dim3(8, 64), dim3(256), 0, stream,
                     Ob, wout_t, bout, out);
}